// Round 11
// baseline (428.077 us; speedup 1.0000x reference)
//
#include <hip/hip_runtime.h>
#include <hip/hip_bf16.h>
#include <cstdint>
#include <cstddef>

#define N_NODES 50000
#define N_EDGES 800000
#define NSEG    (N_NODES * 8)            // 400000 (dst,et) buckets

using frag_t = __attribute__((ext_vector_type(8))) short;   // 8 bf16 (4 VGPRs)
using f32x4  = __attribute__((ext_vector_type(4))) float;   // 4 fp32 acc

typedef const __attribute__((address_space(1))) void* gptr_t;
typedef __attribute__((address_space(3))) void* lptr_t;

__device__ __forceinline__ short f2bf(float x) {
    __hip_bfloat16 h = __float2bfloat16(x);
    return *reinterpret_cast<short*>(&h);
}
__device__ __forceinline__ float bf2f(unsigned int u) {   // low 16 bits = bf16
    union { unsigned int i; float f; } v;
    v.i = u << 16;
    return v.f;
}
__device__ __forceinline__ float bf2f_hi(unsigned int u) {  // high 16 bits = bf16
    union { unsigned int i; float f; } v;
    v.i = u & 0xFFFF0000u;
    return v.f;
}
__device__ __forceinline__ unsigned int packbf2(float lo, float hi) {
    unsigned int a = (unsigned short)f2bf(lo);
    unsigned int b = (unsigned short)f2bf(hi);
    return a | (b << 16);
}

// ============================ CSR build over (dst*8 + et) ============================

__global__ void hist_kernel(const int* __restrict__ dst, const int* __restrict__ et,
                            int* __restrict__ deg8, int E) {
    int e = blockIdx.x * 256 + threadIdx.x;
    if (e < E) atomicAdd(&deg8[dst[e] * 8 + et[e]], 1);
}

__global__ __launch_bounds__(256) void scan_part(const int* __restrict__ deg8,
                                                 int* __restrict__ part, int M) {
    __shared__ int red[256];
    int t = threadIdx.x;
    int idx = blockIdx.x * 1024 + t * 4;
    int s = 0;
    if (idx + 3 < M) {
        int4 d = *(const int4*)(deg8 + idx);
        s = d.x + d.y + d.z + d.w;
    } else {
        for (int c = 0; c < 4; c++) if (idx + c < M) s += deg8[idx + c];
    }
    red[t] = s;
    __syncthreads();
    #pragma unroll
    for (int off = 128; off; off >>= 1) {
        if (t < off) red[t] += red[t + off];
        __syncthreads();
    }
    if (t == 0) part[blockIdx.x] = red[0];
}

__global__ __launch_bounds__(512) void scan_mid(int* __restrict__ part, int nparts,
                                                int* __restrict__ rowp, int M) {
    __shared__ int buf[512];
    int t = threadIdx.x;
    int own = (t < nparts) ? part[t] : 0;
    buf[t] = own;
    __syncthreads();
    for (int off = 1; off < 512; off <<= 1) {
        int v = buf[t];
        int u = (t >= off) ? buf[t - off] : 0;
        __syncthreads();
        buf[t] = v + u;
        __syncthreads();
    }
    if (t < nparts) part[t] = buf[t] - own;    // exclusive
    if (t == 511) rowp[M] = buf[511];          // total
}

__global__ __launch_bounds__(256) void scan_fix(const int* __restrict__ deg8,
                                                const int* __restrict__ part,
                                                int* __restrict__ rowp,
                                                int* __restrict__ cursor, int M) {
    __shared__ int wsum[4];
    int t = threadIdx.x, lane = t & 63, w = t >> 6;
    int idx = blockIdx.x * 1024 + t * 4;
    int v0 = 0, v1 = 0, v2 = 0, v3 = 0;
    if (idx + 3 < M) {
        int4 d = *(const int4*)(deg8 + idx);
        v0 = d.x; v1 = d.y; v2 = d.z; v3 = d.w;
    } else {
        if (idx     < M) v0 = deg8[idx];
        if (idx + 1 < M) v1 = deg8[idx + 1];
        if (idx + 2 < M) v2 = deg8[idx + 2];
        if (idx + 3 < M) v3 = deg8[idx + 3];
    }
    int tsum = v0 + v1 + v2 + v3;
    int sc = tsum;
    #pragma unroll
    for (int off = 1; off < 64; off <<= 1) {
        int u = __shfl_up(sc, off, 64);
        if (lane >= off) sc += u;
    }
    if (lane == 63) wsum[w] = sc;
    __syncthreads();
    int woff = 0;
    for (int i = 0; i < w; i++) woff += wsum[i];
    int excl = part[blockIdx.x] + woff + sc - tsum;
    if (idx     < M) { rowp[idx]     = excl; cursor[idx]     = excl; } excl += v0;
    if (idx + 1 < M) { rowp[idx + 1] = excl; cursor[idx + 1] = excl; } excl += v1;
    if (idx + 2 < M) { rowp[idx + 2] = excl; cursor[idx + 2] = excl; } excl += v2;
    if (idx + 3 < M) { rowp[idx + 3] = excl; cursor[idx + 3] = excl; }
}

__global__ void fill_kernel(const int* __restrict__ src, const int* __restrict__ dst,
                            const int* __restrict__ et, int* __restrict__ cursor,
                            int* __restrict__ sorted, int E) {
    int e = blockIdx.x * 256 + threadIdx.x;
    if (e < E) {
        int pos = atomicAdd(&cursor[dst[e] * 8 + et[e]], 1);
        sorted[pos] = src[e] | (et[e] << 16);
    }
}

// ============================ fp32 tiled GEMM (linear, K=64) -> bf16 hb  + FUSED qk layer-1 ============================
// Block computes the FULL 64x128 output tile, so qk for its 64 nodes is
// computed in-epilogue from the LDS-restaged bf16 values (identical inputs to
// the old qk_table read of hb). Saves a dispatch + 12.8 MB re-read.

__global__ __launch_bounds__(256) void gemm_lin_qk(const float* __restrict__ A,
                                                   const float* __restrict__ B,
                                                   const float* __restrict__ bias,
                                                   const float* __restrict__ wq,
                                                   const float* __restrict__ wk,
                                                   unsigned short* __restrict__ hb,
                                                   float* __restrict__ Q,
                                                   float* __restrict__ Kt, int N) {
    const int Kdim = 64;
    __shared__ float smem[32 * 64 + 32 * 128];     // 24 KB: As | Bs; hlds alias after
    float (*As)[64]  = (float (*)[64])smem;
    float (*Bs)[128] = (float (*)[128])(smem + 32 * 64);
    int t = threadIdx.x;
    int n0 = blockIdx.x * 64;
    int rg = t >> 4, cg = t & 15;
    int an = t >> 2, ak = (t & 3) * 8;
    float acc[4][8] = {};

    for (int k0 = 0; k0 < Kdim; k0 += 32) {
        int gn = n0 + an;
        if (gn < N) {
            const float* ap = A + (size_t)gn * Kdim + k0 + ak;
            float4 v0 = *(const float4*)ap;
            float4 v1 = *(const float4*)(ap + 4);
            As[ak + 0][an] = v0.x; As[ak + 1][an] = v0.y;
            As[ak + 2][an] = v0.z; As[ak + 3][an] = v0.w;
            As[ak + 4][an] = v1.x; As[ak + 5][an] = v1.y;
            As[ak + 6][an] = v1.z; As[ak + 7][an] = v1.w;
        } else {
            #pragma unroll
            for (int c = 0; c < 8; c++) As[ak + c][an] = 0.f;
        }
        {
            int o = t >> 1, kh = (t & 1) * 16;
            const float* bp = B + (size_t)o * Kdim + k0 + kh;
            #pragma unroll
            for (int j = 0; j < 4; j++) {
                float4 v = ((const float4*)bp)[j];
                Bs[kh + j * 4 + 0][o] = v.x;
                Bs[kh + j * 4 + 1][o] = v.y;
                Bs[kh + j * 4 + 2][o] = v.z;
                Bs[kh + j * 4 + 3][o] = v.w;
            }
        }
        __syncthreads();
        #pragma unroll
        for (int k = 0; k < 32; k++) {
            float a[4], b[8];
            *(float4*)&a[0] = *(const float4*)&As[k][rg * 4];
            *(float4*)&b[0] = *(const float4*)&Bs[k][cg * 8];
            *(float4*)&b[4] = *(const float4*)&Bs[k][cg * 8 + 4];
            #pragma unroll
            for (int i = 0; i < 4; i++)
                #pragma unroll
                for (int j = 0; j < 8; j++)
                    acc[i][j] = fmaf(a[i], b[j], acc[i][j]);
        }
        __syncthreads();
    }

    // epilogue: write hb AND restage bf16 tile into LDS (As/Bs now dead)
    unsigned short* hlds = (unsigned short*)smem;   // [64][128] = 16 KB
    #pragma unroll
    for (int i = 0; i < 4; i++) {
        int gn = n0 + rg * 4 + i;
        unsigned short us[8];
        #pragma unroll
        for (int j = 0; j < 8; j++)
            us[j] = (unsigned short)f2bf(acc[i][j] + bias[cg * 8 + j]);
        if (gn < N)
            *(int4*)(hb + (size_t)gn * 128 + cg * 8) = *(int4*)&us[0];
        *(int4*)(hlds + (size_t)(rg * 4 + i) * 128 + cg * 8) = *(int4*)&us[0];
    }
    __syncthreads();

    // qk: node n = t>>2, channel-quarter qq = t&3; 2x shfl_xor reduce over the quad
    {
        int n = t >> 2, qq = t & 3;
        int gn = n0 + n;
        float aq[8] = {}, akk[8] = {};
        const uint2* rowq = (const uint2*)(hlds + (size_t)n * 128 + qq * 32);
        #pragma unroll
        for (int i = 0; i < 8; i++) {
            uint2 d = rowq[i];
            float x0 = bf2f(d.x & 0xFFFFu);
            float x1 = bf2f(d.x >> 16);
            float x2 = bf2f(d.y & 0xFFFFu);
            float x3 = bf2f(d.y >> 16);
            int c = qq * 32 + i * 4;
            #pragma unroll
            for (int r = 0; r < 8; r++) {
                const float* wqr = wq + r * 128 + c;
                const float* wkr = wk + r * 128 + c;
                aq[r]  = fmaf(x0, wqr[0], fmaf(x1, wqr[1], fmaf(x2, wqr[2], fmaf(x3, wqr[3], aq[r]))));
                akk[r] = fmaf(x0, wkr[0], fmaf(x1, wkr[1], fmaf(x2, wkr[2], fmaf(x3, wkr[3], akk[r]))));
            }
        }
        #pragma unroll
        for (int r = 0; r < 8; r++) {
            aq[r]  += __shfl_xor(aq[r], 1, 64);  aq[r]  += __shfl_xor(aq[r], 2, 64);
            akk[r] += __shfl_xor(akk[r], 1, 64); akk[r] += __shfl_xor(akk[r], 2, 64);
        }
        if (qq == 0 && gn < N) {
            float4* qp = (float4*)(Q + (size_t)gn * 8);
            qp[0] = *(float4*)&aq[0];
            qp[1] = *(float4*)&aq[4];
            float4* kp = (float4*)(Kt + (size_t)gn * 8);
            kp[0] = *(float4*)&akk[0];
            kp[1] = *(float4*)&akk[4];
        }
    }
}

// ============================ merged W prep for BOTH layers ============================

__global__ void wprep2_kernel(const float* __restrict__ W1, const float* __restrict__ q1v,
                              const float* __restrict__ k1v,
                              const float* __restrict__ W2, const float* __restrict__ q2v,
                              const float* __restrict__ k2v,
                              short* __restrict__ Bf1, short* __restrict__ Bf2,
                              float* __restrict__ wq1, float* __restrict__ wk1,
                              float* __restrict__ wq2, float* __restrict__ wk2) {
    int g0 = blockIdx.x * 256 + threadIdx.x;       // [0, 266240)
    int layer = (g0 >= 133120) ? 1 : 0;
    int g = g0 - layer * 133120;
    const float* W  = layer ? W2  : W1;
    const float* qv = layer ? q2v : q1v;
    const float* kv = layer ? k2v : k1v;
    short* Bf = layer ? Bf2 : Bf1;
    float* wq = layer ? wq2 : wq1;
    float* wk = layer ? wk2 : wk1;

    if (g < 131072) {
        int kk = g >> 7, o = g & 127;
        float v = W[(size_t)kk * 128 + o];
        Bf[(((size_t)(kk >> 3) * 128) + o) * 8 + (kk & 7)] = f2bf(v);
        return;
    }
    int h = g - 131072;
    if (h < 2048) {
        int which = h >> 10;
        int r = (h >> 7) & 7;
        int i = h & 127;
        const float* vec = which ? kv : qv;
        const float* wrow = W + ((size_t)r * 128 + i) * 128;
        float acc = 0.f;
        #pragma unroll 4
        for (int o = 0; o < 128; o++) acc = fmaf(wrow[o], vec[o], acc);
        (which ? wk : wq)[r * 128 + i] = acc;
    }
}

// ============================ FUSED: softmax-aggregate -> LDS s-tile -> MFMA GEMM (+ optional qk for next layer) ============================
// Structure proven at 75 us (R9): 16-node tile, 512 threads (8 waves), ~36 KB
// LDS -> 4 blocks/CU = 32 waves/CU. Phase 1: work-stealing rows, low-VALU
// stash. Phase 2 (one barrier): wave w = one 16x16 col-tile, B direct from
// L2-resident Bf. NEW: when Qout != null (layer 1), the epilogue also computes
// next-layer Q/K for the block's 16 complete rows via a 4 KB alias of the
// (dead) s_tile -- replaces the qk_table dispatch + 12.8 MB hb2 re-read.
// Qout/Kout are SEPARATE buffers (other blocks still read layer-1 Q/K).

__global__ __launch_bounds__(512, 8) void fused_agg_gemm(
        const unsigned short* __restrict__ hb,
        const float* __restrict__ Q,
        const float* __restrict__ Kt,
        const int* __restrict__ rowp8,
        const int* __restrict__ sorted,
        const short* __restrict__ Bf,
        const float* __restrict__ bias,
        const float* __restrict__ wqn,
        const float* __restrict__ wkn,
        float* __restrict__ Qout,
        float* __restrict__ Kout,
        float* __restrict__ Cout,
        unsigned short* __restrict__ hbout,
        int N, int relu) {
    __shared__ short s_tile[16 * 1024];   // 32 KB: [kb 0..127][row 0..15][8], swizzled
    __shared__ uint2 stash[8][64];        // 4 KB: per-wave (byte-off, wgt|et) edge list
    __shared__ int wcnt;                  // work-stealing row counter
    unsigned int* sdw = (unsigned int*)s_tile;
    const char* hbB = (const char*)hb;

    int t = threadIdx.x;
    int w = t >> 6, lane = t & 63;
    int lhi = lane >> 4, llo = lane & 15;
    unsigned int lv4 = (unsigned int)lane * 4u;
    int n0 = blockIdx.x * 16;

    if (t == 0) wcnt = 0;
    __syncthreads();

    // ---------------- phase 1: softmax + weighted gather, flush s rows to LDS ----------------
    for (;;) {
        int row;
        if (lane == 0) row = atomicAdd(&wcnt, 1);
        row = __shfl(row, 0, 64);
        if (row >= 16) break;
        int n = n0 + row;
        float2 acc = {0.f, 0.f};
        int rcur = 0;
        auto flushw = [&](unsigned int val) {
            int kb = rcur * 16 + (lane >> 2);
            sdw[kb * 64 + ((row ^ (kb & 15)) * 4) + (lane & 3)] = val;
        };
        if (n >= N) {                                   // tail: zero pad rows
            while (rcur < 8) { flushw(0u); rcur++; }
            continue;
        }
        int beg = rowp8[n * 8];
        int end = rowp8[n * 8 + 8];
        int deg = end - beg;
        if (deg == 0) {
            while (rcur < 8) { flushw(0u); rcur++; }
            continue;
        }

        if (deg <= 64) {
            int pk = 0;
            float a = -INFINITY;
            if (lane < deg) {
                pk = sorted[beg + lane];
                int srcn = pk & 0xFFFF, etj = pk >> 16;
                a = Q[(size_t)n * 8 + etj] + Kt[(size_t)srcn * 8 + etj];
                a = (a > 0.f) ? a : 0.2f * a;                 // leaky_relu 0.2
            }
            float m = a;
            #pragma unroll
            for (int off = 32; off; off >>= 1) m = fmaxf(m, __shfl_xor(m, off, 64));
            float e = (lane < deg) ? __expf(a - m) : 0.f;
            float sum = e;
            #pragma unroll
            for (int off = 32; off; off >>= 1) sum += __shfl_xor(sum, off, 64);
            float wgt = e / (sum + 1e-16f);
            stash[w][lane] = make_uint2((unsigned int)(pk & 0xFFFF) << 8,
                                        (__float_as_uint(wgt) & ~7u) | (unsigned int)(pk >> 16));

            int j = 0;
            for (; j + 8 <= deg; j += 8) {
                uint2 ee[8]; unsigned int dd[8];
                #pragma unroll
                for (int i = 0; i < 8; i++) ee[i] = stash[w][j + i];
                #pragma unroll
                for (int i = 0; i < 8; i++)
                    dd[i] = *(const unsigned int*)(hbB + (ee[i].x | lv4));
                #pragma unroll
                for (int i = 0; i < 8; i++) {
                    int e0 = (int)(ee[i].y & 7u);
                    float w0 = __uint_as_float(ee[i].y);
                    while (rcur < e0) { flushw(packbf2(acc.x, acc.y)); acc.x = acc.y = 0.f; rcur++; }
                    acc.x = fmaf(w0, bf2f(dd[i]),    acc.x);
                    acc.y = fmaf(w0, bf2f_hi(dd[i]), acc.y);
                }
            }
            for (; j < deg; j++) {
                uint2 e1 = stash[w][j];
                unsigned int d0 = *(const unsigned int*)(hbB + (e1.x | lv4));
                int e0 = (int)(e1.y & 7u);
                float w0 = __uint_as_float(e1.y);
                while (rcur < e0) { flushw(packbf2(acc.x, acc.y)); acc.x = acc.y = 0.f; rcur++; }
                acc.x = fmaf(w0, bf2f(d0),    acc.x);
                acc.y = fmaf(w0, bf2f_hi(d0), acc.y);
            }
            while (rcur < 8) { flushw(packbf2(acc.x, acc.y)); acc.x = acc.y = 0.f; rcur++; }
        } else {
            // generic path (deg > 64): chunked, logits recomputed per pass
            auto logit = [&](int j) -> float {
                int pk2 = sorted[beg + j];
                int srcn = pk2 & 0xFFFF, etj = pk2 >> 16;
                float aa = Q[(size_t)n * 8 + etj] + Kt[(size_t)srcn * 8 + etj];
                return (aa > 0.f) ? aa : 0.2f * aa;
            };
            float m = -INFINITY;
            for (int j = lane; j < deg; j += 64) m = fmaxf(m, logit(j));
            #pragma unroll
            for (int off = 32; off; off >>= 1) m = fmaxf(m, __shfl_xor(m, off, 64));
            float sum = 0.f;
            for (int j = lane; j < deg; j += 64) sum += __expf(logit(j) - m);
            #pragma unroll
            for (int off = 32; off; off >>= 1) sum += __shfl_xor(sum, off, 64);
            float inv = 1.f / (sum + 1e-16f);

            for (int j0 = 0; j0 < deg; j0 += 64) {
                int cnt = min(64, deg - j0);
                if (lane < cnt) {
                    int pk = sorted[beg + j0 + lane];
                    int srcn = pk & 0xFFFF, etj = pk >> 16;
                    float aa = Q[(size_t)n * 8 + etj] + Kt[(size_t)srcn * 8 + etj];
                    aa = (aa > 0.f) ? aa : 0.2f * aa;
                    float wgt = __expf(aa - m) * inv;
                    stash[w][lane] = make_uint2((unsigned int)srcn << 8,
                                                (__float_as_uint(wgt) & ~7u) | (unsigned int)etj);
                }
                for (int j = 0; j < cnt; j++) {
                    uint2 e1 = stash[w][j];
                    unsigned int d0 = *(const unsigned int*)(hbB + (e1.x | lv4));
                    int e0 = (int)(e1.y & 7u);
                    float w0 = __uint_as_float(e1.y);
                    while (rcur < e0) { flushw(packbf2(acc.x, acc.y)); acc.x = acc.y = 0.f; rcur++; }
                    acc.x = fmaf(w0, bf2f(d0),    acc.x);
                    acc.y = fmaf(w0, bf2f_hi(d0), acc.y);
                }
            }
            while (rcur < 8) { flushw(packbf2(acc.x, acc.y)); acc.x = acc.y = 0.f; rcur++; }
        }
    }
    __syncthreads();

    // ---------------- phase 2: GEMM 16x1024 @ 1024x128, B direct from global ----------------
    int ctb = w;
    f32x4 acc0 = {};
    const char* BfB = (const char*)Bf;
    #pragma unroll 4
    for (int kq = 0; kq < 32; kq++) {                        // K-quads of 4 kb (K=32)
        int kb = kq * 4 + lhi;
        int d = kb * 64 + ((llo ^ (kb & 15)) * 4);           // swizzled A dword index
        frag_t a  = *(const frag_t*)(&sdw[d]);
        frag_t b0 = *(const frag_t*)(BfB + ((size_t)kb * 128 + ctb * 16 + llo) * 16);
        acc0 = __builtin_amdgcn_mfma_f32_16x16x32_bf16(a, b0, acc0, 0, 0, 0);
    }

    // epilogue: C/D mapping col = lane&15, row = (lane>>4)*4 + reg
    unsigned short us2[4];
    int col = ctb * 16 + llo;
    {
        float bv = bias[col];
        #pragma unroll
        for (int rg = 0; rg < 4; rg++) {
            float v = acc0[rg] + bv;
            if (relu) v = fmaxf(v, 0.f);
            us2[rg] = (unsigned short)f2bf(v);
            int rown = n0 + lhi * 4 + rg;
            if (rown < N) {
                if (Cout)  Cout[(size_t)rown * 128 + col] = v;
                if (hbout) hbout[(size_t)rown * 128 + col] = us2[rg];
            }
        }
    }

    // ---------------- optional: next-layer qk from the block's 16 complete rows ----------------
    if (Qout) {                                   // uniform branch (kernel arg)
        __syncthreads();                          // all phase-2 s_tile reads done
        unsigned short* qlds = (unsigned short*)s_tile;   // [16][128] = 4 KB alias
        #pragma unroll
        for (int rg = 0; rg < 4; rg++)
            qlds[(size_t)(lhi * 4 + rg) * 128 + col] = us2[rg];
        __syncthreads();
        if (t < 256) {
            int n = t >> 4;                       // 0..15
            int rr = (t >> 1) & 7;                // relation
            int which = t & 1;                    // 0 = Q, 1 = K
            int gn = n0 + n;
            if (gn < N) {
                const float* wv = which ? wkn : wqn;
                const uint2* rowq = (const uint2*)(qlds + (size_t)n * 128);
                float acc = 0.f;
                #pragma unroll 8
                for (int i = 0; i < 32; i++) {
                    uint2 d = rowq[i];
                    float x0 = bf2f(d.x & 0xFFFFu);
                    float x1 = bf2f(d.x >> 16);
                    float x2 = bf2f(d.y & 0xFFFFu);
                    float x3 = bf2f(d.y >> 16);
                    const float* wv4 = wv + rr * 128 + i * 4;
                    acc = fmaf(x0, wv4[0], fmaf(x1, wv4[1], fmaf(x2, wv4[2], fmaf(x3, wv4[3], acc))));
                }
                (which ? Kout : Qout)[(size_t)gn * 8 + rr] = acc;
            }
        }
    }
}

// ============================ launch ============================

extern "C" void kernel_launch(void* const* d_in, const int* in_sizes, int n_in,
                              void* d_out, int out_size, void* d_ws, size_t ws_size,
                              hipStream_t stream) {
    const float* z     = (const float*)d_in[0];
    const float* lin_w = (const float*)d_in[1];
    const float* lin_b = (const float*)d_in[2];
    const float* w1    = (const float*)d_in[3];
    const float* q1    = (const float*)d_in[4];
    const float* k1    = (const float*)d_in[5];
    const float* b1    = (const float*)d_in[6];
    const float* w2    = (const float*)d_in[7];
    const float* q2    = (const float*)d_in[8];
    const float* k2    = (const float*)d_in[9];
    const float* b2    = (const float*)d_in[10];
    const int*   ei    = (const int*)d_in[11];
    const int*   et    = (const int*)d_in[12];
    float* out = (float*)d_out;

    char* ws = (char*)d_ws;
    size_t off = 0;
    auto alloc = [&](size_t bytes) -> void* {
        void* p = ws + off;
        off += (bytes + 255) & ~(size_t)255;
        return p;
    };
    unsigned short* hb  = (unsigned short*)alloc((size_t)N_NODES * 128 * 2);  // 12.8 MB
    unsigned short* hb2 = (unsigned short*)alloc((size_t)N_NODES * 128 * 2);  // 12.8 MB
    float* Q     = (float*)alloc((size_t)N_NODES * 8 * 4);
    float* K     = (float*)alloc((size_t)N_NODES * 8 * 4);
    float* Qb    = (float*)alloc((size_t)N_NODES * 8 * 4);   // layer-2 q/k (separate:
    float* Kb    = (float*)alloc((size_t)N_NODES * 8 * 4);   // fused1 still reads Q/K)
    int* sorted  = (int*)alloc((size_t)N_EDGES * 4);
    int* deg8    = (int*)alloc((size_t)NSEG * 4);
    int* rowp8   = (int*)alloc((size_t)(NSEG + 1) * 4);
    int* cursor8 = (int*)alloc((size_t)NSEG * 4);
    int* part    = (int*)alloc(1024 * 4);
    float* wq1   = (float*)alloc(8 * 128 * 4);
    float* wk1   = (float*)alloc(8 * 128 * 4);
    float* wq2   = (float*)alloc(8 * 128 * 4);
    float* wk2   = (float*)alloc(8 * 128 * 4);
    short* Bf1   = (short*)alloc((size_t)1024 * 128 * 2);       // 256 KB bf16 blocked
    short* Bf2   = (short*)alloc((size_t)1024 * 128 * 2);       // 256 KB bf16 blocked

    const int* src = ei;
    const int* dst = ei + N_EDGES;

    const int M = NSEG;
    const int nparts = (M + 1023) / 1024;   // 391

    // CSR build over (dst,et) -- proven multi-dispatch chain
    hipMemsetAsync(deg8, 0, (size_t)M * 4, stream);
    hist_kernel<<<(N_EDGES + 255) / 256, 256, 0, stream>>>(dst, et, deg8, N_EDGES);
    scan_part<<<nparts, 256, 0, stream>>>(deg8, part, M);
    scan_mid<<<1, 512, 0, stream>>>(part, nparts, rowp8, M);
    scan_fix<<<nparts, 256, 0, stream>>>(deg8, part, rowp8, cursor8, M);
    fill_kernel<<<(N_EDGES + 255) / 256, 256, 0, stream>>>(src, dst, et, cursor8, sorted, N_EDGES);

    // W prep for BOTH layers (must precede gemm_lin_qk: it consumes wq1/wk1)
    wprep2_kernel<<<(2 * 133120 + 255) / 256, 256, 0, stream>>>(
        w1, q1, k1, w2, q2, k2, Bf1, Bf2, wq1, wk1, wq2, wk2);

    // h = z @ lin_w.T + lin_b  (bf16 hb) + fused layer-1 qk tables
    gemm_lin_qk<<<(N_NODES + 63) / 64, 256, 0, stream>>>(z, lin_w, lin_b, wq1, wk1,
                                                         hb, Q, K, N_NODES);

    int fgrid = (N_NODES + 15) / 16;     // 3125

    // ---- layer 1: hb -> hb2 (relu, bf16) + layer-2 qk tables (Qb/Kb)
    fused_agg_gemm<<<fgrid, 512, 0, stream>>>(hb, Q, K, rowp8, sorted, Bf1, b1,
                                              wq2, wk2, Qb, Kb,
                                              (float*)nullptr, hb2, N_NODES, 1);

    // ---- layer 2: hb2 -> out (no relu, fp32)
    fused_agg_gemm<<<fgrid, 512, 0, stream>>>(hb2, Qb, Kb, rowp8, sorted, Bf2, b2,
                                              (const float*)nullptr, (const float*)nullptr,
                                              (float*)nullptr, (float*)nullptr,
                                              out, (unsigned short*)nullptr, N_NODES, 0);
}

// Round 12
// 348.972 us; speedup vs baseline: 1.2267x; 1.2267x over previous
//
#include <hip/hip_runtime.h>
#include <hip/hip_bf16.h>
#include <cstdint>
#include <cstddef>

#define N_NODES 50000
#define N_EDGES 800000
#define NSEG    (N_NODES * 8)            // 400000 (dst,et) buckets
#define HIST_BLKS 3125                   // ceil(N_EDGES/256)
#define WPREP_BLKS 1040                  // ceil(2*133120/256)
#define GLIN_BLKS 782                    // ceil(N_NODES/64)
#define QK_BLKS 196                      // ceil(N_NODES/256)

using frag_t = __attribute__((ext_vector_type(8))) short;   // 8 bf16 (4 VGPRs)
using f32x4  = __attribute__((ext_vector_type(4))) float;   // 4 fp32 acc

typedef const __attribute__((address_space(1))) void* gptr_t;
typedef __attribute__((address_space(3))) void* lptr_t;

__device__ __forceinline__ short f2bf(float x) {
    __hip_bfloat16 h = __float2bfloat16(x);
    return *reinterpret_cast<short*>(&h);
}
__device__ __forceinline__ float bf2f(unsigned int u) {   // low 16 bits = bf16
    union { unsigned int i; float f; } v;
    v.i = u << 16;
    return v.f;
}
__device__ __forceinline__ float bf2f_hi(unsigned int u) {  // high 16 bits = bf16
    union { unsigned int i; float f; } v;
    v.i = u & 0xFFFF0000u;
    return v.f;
}
__device__ __forceinline__ unsigned int packbf2(float lo, float hi) {
    unsigned int a = (unsigned short)f2bf(lo);
    unsigned int b = (unsigned short)f2bf(hi);
    return a | (b << 16);
}

// ============================ MEGA-A: hist | wprep2 | gemm_lin (independent, block-ranged) ============================
// Grid-fusion of three mutually independent kernels (disjoint in/out) into one
// dispatch — saves 2 launch gaps (~7-10 us each, measured R7->R9). Each branch
// is the R9-proven body, block-uniform select on blockIdx.

__global__ __launch_bounds__(256) void prep_mega(
        const int* __restrict__ dst, const int* __restrict__ et,
        int* __restrict__ deg8,
        const float* __restrict__ W1, const float* __restrict__ q1v,
        const float* __restrict__ k1v,
        const float* __restrict__ W2, const float* __restrict__ q2v,
        const float* __restrict__ k2v,
        short* __restrict__ Bf1, short* __restrict__ Bf2,
        float* __restrict__ wq1, float* __restrict__ wk1,
        float* __restrict__ wq2, float* __restrict__ wk2,
        const float* __restrict__ z, const float* __restrict__ lin_w,
        const float* __restrict__ lin_b,
        unsigned short* __restrict__ hb) {
    __shared__ float smem[32 * 64 + 32 * 128];   // 24 KB (gemm_lin branch only)
    int b = blockIdx.x, t = threadIdx.x;

    // ---- branch 1: histogram over (dst*8+et)
    if (b < HIST_BLKS) {
        int e = b * 256 + t;
        if (e < N_EDGES) atomicAdd(&deg8[dst[e] * 8 + et[e]], 1);
        return;
    }
    b -= HIST_BLKS;

    // ---- branch 2: W prep for both layers
    if (b < WPREP_BLKS) {
        int g0 = b * 256 + t;                      // [0, 266240)
        int layer = (g0 >= 133120) ? 1 : 0;
        int g = g0 - layer * 133120;
        const float* W  = layer ? W2  : W1;
        const float* qv = layer ? q2v : q1v;
        const float* kv = layer ? k2v : k1v;
        short* Bf = layer ? Bf2 : Bf1;
        float* wq = layer ? wq2 : wq1;
        float* wk = layer ? wk2 : wk1;
        if (g < 131072) {
            int kk = g >> 7, o = g & 127;
            float v = W[(size_t)kk * 128 + o];
            Bf[(((size_t)(kk >> 3) * 128) + o) * 8 + (kk & 7)] = f2bf(v);
        } else {
            int h = g - 131072;
            if (h < 2048) {
                int which = h >> 10;
                int r = (h >> 7) & 7;
                int i = h & 127;
                const float* vec = which ? kv : qv;
                const float* wrow = W + ((size_t)r * 128 + i) * 128;
                float acc = 0.f;
                #pragma unroll 4
                for (int o = 0; o < 128; o++) acc = fmaf(wrow[o], vec[o], acc);
                (which ? wk : wq)[r * 128 + i] = acc;
            }
        }
        return;
    }
    b -= WPREP_BLKS;

    // ---- branch 3: gemm_lin — h = z @ lin_w.T + lin_b -> bf16 hb (R9 body)
    {
        float (*As)[64]  = (float (*)[64])smem;
        float (*Bs)[128] = (float (*)[128])(smem + 32 * 64);
        const int Kdim = 64;
        int n0 = b * 64;
        int rg = t >> 4, cg = t & 15;
        int an = t >> 2, ak = (t & 3) * 8;
        float acc[4][8] = {};

        for (int k0 = 0; k0 < Kdim; k0 += 32) {
            int gn = n0 + an;
            if (gn < N_NODES) {
                const float* ap = z + (size_t)gn * Kdim + k0 + ak;
                float4 v0 = *(const float4*)ap;
                float4 v1 = *(const float4*)(ap + 4);
                As[ak + 0][an] = v0.x; As[ak + 1][an] = v0.y;
                As[ak + 2][an] = v0.z; As[ak + 3][an] = v0.w;
                As[ak + 4][an] = v1.x; As[ak + 5][an] = v1.y;
                As[ak + 6][an] = v1.z; As[ak + 7][an] = v1.w;
            } else {
                #pragma unroll
                for (int c = 0; c < 8; c++) As[ak + c][an] = 0.f;
            }
            {
                int o = t >> 1, kh = (t & 1) * 16;
                const float* bp = lin_w + (size_t)o * Kdim + k0 + kh;
                #pragma unroll
                for (int j = 0; j < 4; j++) {
                    float4 v = ((const float4*)bp)[j];
                    Bs[kh + j * 4 + 0][o] = v.x;
                    Bs[kh + j * 4 + 1][o] = v.y;
                    Bs[kh + j * 4 + 2][o] = v.z;
                    Bs[kh + j * 4 + 3][o] = v.w;
                }
            }
            __syncthreads();
            #pragma unroll
            for (int k = 0; k < 32; k++) {
                float a[4], bb[8];
                *(float4*)&a[0] = *(const float4*)&As[k][rg * 4];
                *(float4*)&bb[0] = *(const float4*)&Bs[k][cg * 8];
                *(float4*)&bb[4] = *(const float4*)&Bs[k][cg * 8 + 4];
                #pragma unroll
                for (int i = 0; i < 4; i++)
                    #pragma unroll
                    for (int j = 0; j < 8; j++)
                        acc[i][j] = fmaf(a[i], bb[j], acc[i][j]);
            }
            __syncthreads();
        }
        #pragma unroll
        for (int i = 0; i < 4; i++) {
            int gn = n0 + rg * 4 + i;
            if (gn < N_NODES) {
                unsigned short us[8];
                #pragma unroll
                for (int j = 0; j < 8; j++)
                    us[j] = (unsigned short)f2bf(acc[i][j] + lin_b[cg * 8 + j]);
                *(int4*)(hb + (size_t)gn * 128 + cg * 8) = *(int4*)&us[0];
            }
        }
    }
}

// ============================ scan chain (unchanged R9) ============================

__global__ __launch_bounds__(256) void scan_part(const int* __restrict__ deg8,
                                                 int* __restrict__ part, int M) {
    __shared__ int red[256];
    int t = threadIdx.x;
    int idx = blockIdx.x * 1024 + t * 4;
    int s = 0;
    if (idx + 3 < M) {
        int4 d = *(const int4*)(deg8 + idx);
        s = d.x + d.y + d.z + d.w;
    } else {
        for (int c = 0; c < 4; c++) if (idx + c < M) s += deg8[idx + c];
    }
    red[t] = s;
    __syncthreads();
    #pragma unroll
    for (int off = 128; off; off >>= 1) {
        if (t < off) red[t] += red[t + off];
        __syncthreads();
    }
    if (t == 0) part[blockIdx.x] = red[0];
}

__global__ __launch_bounds__(512) void scan_mid(int* __restrict__ part, int nparts,
                                                int* __restrict__ rowp, int M) {
    __shared__ int buf[512];
    int t = threadIdx.x;
    int own = (t < nparts) ? part[t] : 0;
    buf[t] = own;
    __syncthreads();
    for (int off = 1; off < 512; off <<= 1) {
        int v = buf[t];
        int u = (t >= off) ? buf[t - off] : 0;
        __syncthreads();
        buf[t] = v + u;
        __syncthreads();
    }
    if (t < nparts) part[t] = buf[t] - own;    // exclusive
    if (t == 511) rowp[M] = buf[511];          // total
}

__global__ __launch_bounds__(256) void scan_fix(const int* __restrict__ deg8,
                                                const int* __restrict__ part,
                                                int* __restrict__ rowp,
                                                int* __restrict__ cursor, int M) {
    __shared__ int wsum[4];
    int t = threadIdx.x, lane = t & 63, w = t >> 6;
    int idx = blockIdx.x * 1024 + t * 4;
    int v0 = 0, v1 = 0, v2 = 0, v3 = 0;
    if (idx + 3 < M) {
        int4 d = *(const int4*)(deg8 + idx);
        v0 = d.x; v1 = d.y; v2 = d.z; v3 = d.w;
    } else {
        if (idx     < M) v0 = deg8[idx];
        if (idx + 1 < M) v1 = deg8[idx + 1];
        if (idx + 2 < M) v2 = deg8[idx + 2];
        if (idx + 3 < M) v3 = deg8[idx + 3];
    }
    int tsum = v0 + v1 + v2 + v3;
    int sc = tsum;
    #pragma unroll
    for (int off = 1; off < 64; off <<= 1) {
        int u = __shfl_up(sc, off, 64);
        if (lane >= off) sc += u;
    }
    if (lane == 63) wsum[w] = sc;
    __syncthreads();
    int woff = 0;
    for (int i = 0; i < w; i++) woff += wsum[i];
    int excl = part[blockIdx.x] + woff + sc - tsum;
    if (idx     < M) { rowp[idx]     = excl; cursor[idx]     = excl; } excl += v0;
    if (idx + 1 < M) { rowp[idx + 1] = excl; cursor[idx + 1] = excl; } excl += v1;
    if (idx + 2 < M) { rowp[idx + 2] = excl; cursor[idx + 2] = excl; } excl += v2;
    if (idx + 3 < M) { rowp[idx + 3] = excl; cursor[idx + 3] = excl; }
}

// ============================ MEGA-B: fill | qk-layer-1 (independent, block-ranged) ============================
// fill needs cursor (scan_fix); qk1 needs hb + wq1/wk1 (prep_mega). Both ready.

__global__ __launch_bounds__(256) void fill_qk(
        const int* __restrict__ src, const int* __restrict__ dst,
        const int* __restrict__ et, int* __restrict__ cursor,
        int* __restrict__ sorted,
        const unsigned short* __restrict__ xb,
        const float* __restrict__ wq, const float* __restrict__ wk,
        float* __restrict__ Q, float* __restrict__ K) {
    int b = blockIdx.x, t = threadIdx.x;

    if (b < HIST_BLKS) {               // ---- fill payloads
        int e = b * 256 + t;
        if (e < N_EDGES) {
            int pos = atomicAdd(&cursor[dst[e] * 8 + et[e]], 1);
            sorted[pos] = src[e] | (et[e] << 16);
        }
        return;
    }
    b -= HIST_BLKS;

    // ---- qk layer 1: thread-per-node (R9 qk_table body)
    int n = b * 256 + t;
    if (n >= N_NODES) return;
    const uint2* row = (const uint2*)(xb + (size_t)n * 128);
    float aq[8] = {}, ak[8] = {};
    for (int i = 0; i < 32; i++) {
        uint2 d = row[i];
        float x0 = bf2f(d.x & 0xFFFFu);
        float x1 = bf2f(d.x >> 16);
        float x2 = bf2f(d.y & 0xFFFFu);
        float x3 = bf2f(d.y >> 16);
        int c = i * 4;
        #pragma unroll
        for (int r = 0; r < 8; r++) {
            const float* wqr = wq + r * 128 + c;
            const float* wkr = wk + r * 128 + c;
            aq[r] = fmaf(x0, wqr[0], fmaf(x1, wqr[1], fmaf(x2, wqr[2], fmaf(x3, wqr[3], aq[r]))));
            ak[r] = fmaf(x0, wkr[0], fmaf(x1, wkr[1], fmaf(x2, wkr[2], fmaf(x3, wkr[3], ak[r]))));
        }
    }
    float4* qp = (float4*)(Q + (size_t)n * 8);
    qp[0] = *(float4*)&aq[0];
    qp[1] = *(float4*)&aq[4];
    float4* kp = (float4*)(K + (size_t)n * 8);
    kp[0] = *(float4*)&ak[0];
    kp[1] = *(float4*)&ak[4];
}

// ============================ qk table (layer 2, standalone — unchanged R9) ============================

__global__ __launch_bounds__(256) void qk_table_kernel(const unsigned short* __restrict__ xb,
                                                       const float* __restrict__ wq,
                                                       const float* __restrict__ wk,
                                                       float* __restrict__ Q,
                                                       float* __restrict__ K, int N) {
    int n = blockIdx.x * 256 + threadIdx.x;
    if (n >= N) return;
    const uint2* row = (const uint2*)(xb + (size_t)n * 128);
    float aq[8] = {}, ak[8] = {};
    for (int i = 0; i < 32; i++) {
        uint2 d = row[i];
        float x0 = bf2f(d.x & 0xFFFFu);
        float x1 = bf2f(d.x >> 16);
        float x2 = bf2f(d.y & 0xFFFFu);
        float x3 = bf2f(d.y >> 16);
        int c = i * 4;
        #pragma unroll
        for (int r = 0; r < 8; r++) {
            const float* wqr = wq + r * 128 + c;
            const float* wkr = wk + r * 128 + c;
            aq[r] = fmaf(x0, wqr[0], fmaf(x1, wqr[1], fmaf(x2, wqr[2], fmaf(x3, wqr[3], aq[r]))));
            ak[r] = fmaf(x0, wkr[0], fmaf(x1, wkr[1], fmaf(x2, wkr[2], fmaf(x3, wkr[3], ak[r]))));
        }
    }
    float4* qp = (float4*)(Q + (size_t)n * 8);
    qp[0] = *(float4*)&aq[0];
    qp[1] = *(float4*)&aq[4];
    float4* kp = (float4*)(K + (size_t)n * 8);
    kp[0] = *(float4*)&ak[0];
    kp[1] = *(float4*)&ak[4];
}

// ============================ FUSED: softmax-aggregate into LDS s-tile, then MFMA GEMM ============================
// EXACT R9 body (proven 75 us): 16-node tile, 512 threads (8 waves), ~36 KB
// LDS -> 4 blocks/CU = 32 waves/CU. Phase 1: work-stealing rows, low-VALU
// stash (byte-off, wgt|et-in-mantissa-LSBs). Phase 2 (one barrier): wave w =
// one 16x16 col-tile, B direct from L2-resident Bf. (R11's in-epilogue qk
// fusion regressed both layers ~75->117 us — reverted.)

__global__ __launch_bounds__(512, 8) void fused_agg_gemm(
        const unsigned short* __restrict__ hb,
        const float* __restrict__ Q,
        const float* __restrict__ Kt,
        const int* __restrict__ rowp8,
        const int* __restrict__ sorted,
        const short* __restrict__ Bf,
        const float* __restrict__ bias,
        float* __restrict__ Cout,
        unsigned short* __restrict__ hbout,
        int N, int relu) {
    __shared__ short s_tile[16 * 1024];   // 32 KB: [kb 0..127][row 0..15][8], swizzled
    __shared__ uint2 stash[8][64];        // 4 KB: per-wave (byte-off, wgt|et) edge list
    __shared__ int wcnt;                  // work-stealing row counter
    unsigned int* sdw = (unsigned int*)s_tile;
    const char* hbB = (const char*)hb;

    int t = threadIdx.x;
    int w = t >> 6, lane = t & 63;
    int lhi = lane >> 4, llo = lane & 15;
    unsigned int lv4 = (unsigned int)lane * 4u;
    int n0 = blockIdx.x * 16;

    if (t == 0) wcnt = 0;
    __syncthreads();

    // ---------------- phase 1: softmax + weighted gather, flush s rows to LDS ----------------
    for (;;) {
        int row;
        if (lane == 0) row = atomicAdd(&wcnt, 1);
        row = __shfl(row, 0, 64);
        if (row >= 16) break;
        int n = n0 + row;
        float2 acc = {0.f, 0.f};
        int rcur = 0;
        auto flushw = [&](unsigned int val) {
            int kb = rcur * 16 + (lane >> 2);
            sdw[kb * 64 + ((row ^ (kb & 15)) * 4) + (lane & 3)] = val;
        };
        if (n >= N) {                                   // tail: zero pad rows
            while (rcur < 8) { flushw(0u); rcur++; }
            continue;
        }
        int beg = rowp8[n * 8];
        int end = rowp8[n * 8 + 8];
        int deg = end - beg;
        if (deg == 0) {
            while (rcur < 8) { flushw(0u); rcur++; }
            continue;
        }

        if (deg <= 64) {
            int pk = 0;
            float a = -INFINITY;
            if (lane < deg) {
                pk = sorted[beg + lane];
                int srcn = pk & 0xFFFF, etj = pk >> 16;
                a = Q[(size_t)n * 8 + etj] + Kt[(size_t)srcn * 8 + etj];
                a = (a > 0.f) ? a : 0.2f * a;                 // leaky_relu 0.2
            }
            float m = a;
            #pragma unroll
            for (int off = 32; off; off >>= 1) m = fmaxf(m, __shfl_xor(m, off, 64));
            float e = (lane < deg) ? __expf(a - m) : 0.f;
            float sum = e;
            #pragma unroll
            for (int off = 32; off; off >>= 1) sum += __shfl_xor(sum, off, 64);
            float wgt = e / (sum + 1e-16f);
            stash[w][lane] = make_uint2((unsigned int)(pk & 0xFFFF) << 8,
                                        (__float_as_uint(wgt) & ~7u) | (unsigned int)(pk >> 16));

            int j = 0;
            for (; j + 8 <= deg; j += 8) {
                uint2 ee[8]; unsigned int dd[8];
                #pragma unroll
                for (int i = 0; i < 8; i++) ee[i] = stash[w][j + i];
                #pragma unroll
                for (int i = 0; i < 8; i++)
                    dd[i] = *(const unsigned int*)(hbB + (ee[i].x | lv4));
                #pragma unroll
                for (int i = 0; i < 8; i++) {
                    int e0 = (int)(ee[i].y & 7u);
                    float w0 = __uint_as_float(ee[i].y);
                    while (rcur < e0) { flushw(packbf2(acc.x, acc.y)); acc.x = acc.y = 0.f; rcur++; }
                    acc.x = fmaf(w0, bf2f(dd[i]),    acc.x);
                    acc.y = fmaf(w0, bf2f_hi(dd[i]), acc.y);
                }
            }
            for (; j < deg; j++) {
                uint2 e1 = stash[w][j];
                unsigned int d0 = *(const unsigned int*)(hbB + (e1.x | lv4));
                int e0 = (int)(e1.y & 7u);
                float w0 = __uint_as_float(e1.y);
                while (rcur < e0) { flushw(packbf2(acc.x, acc.y)); acc.x = acc.y = 0.f; rcur++; }
                acc.x = fmaf(w0, bf2f(d0),    acc.x);
                acc.y = fmaf(w0, bf2f_hi(d0), acc.y);
            }
            while (rcur < 8) { flushw(packbf2(acc.x, acc.y)); acc.x = acc.y = 0.f; rcur++; }
        } else {
            // generic path (deg > 64): chunked, logits recomputed per pass
            auto logit = [&](int j) -> float {
                int pk2 = sorted[beg + j];
                int srcn = pk2 & 0xFFFF, etj = pk2 >> 16;
                float aa = Q[(size_t)n * 8 + etj] + Kt[(size_t)srcn * 8 + etj];
                return (aa > 0.f) ? aa : 0.2f * aa;
            };
            float m = -INFINITY;
            for (int j = lane; j < deg; j += 64) m = fmaxf(m, logit(j));
            #pragma unroll
            for (int off = 32; off; off >>= 1) m = fmaxf(m, __shfl_xor(m, off, 64));
            float sum = 0.f;
            for (int j = lane; j < deg; j += 64) sum += __expf(logit(j) - m);
            #pragma unroll
            for (int off = 32; off; off >>= 1) sum += __shfl_xor(sum, off, 64);
            float inv = 1.f / (sum + 1e-16f);

            for (int j0 = 0; j0 < deg; j0 += 64) {
                int cnt = min(64, deg - j0);
                if (lane < cnt) {
                    int pk = sorted[beg + j0 + lane];
                    int srcn = pk & 0xFFFF, etj = pk >> 16;
                    float aa = Q[(size_t)n * 8 + etj] + Kt[(size_t)srcn * 8 + etj];
                    aa = (aa > 0.f) ? aa : 0.2f * aa;
                    float wgt = __expf(aa - m) * inv;
                    stash[w][lane] = make_uint2((unsigned int)srcn << 8,
                                                (__float_as_uint(wgt) & ~7u) | (unsigned int)etj);
                }
                for (int j = 0; j < cnt; j++) {
                    uint2 e1 = stash[w][j];
                    unsigned int d0 = *(const unsigned int*)(hbB + (e1.x | lv4));
                    int e0 = (int)(e1.y & 7u);
                    float w0 = __uint_as_float(e1.y);
                    while (rcur < e0) { flushw(packbf2(acc.x, acc.y)); acc.x = acc.y = 0.f; rcur++; }
                    acc.x = fmaf(w0, bf2f(d0),    acc.x);
                    acc.y = fmaf(w0, bf2f_hi(d0), acc.y);
                }
            }
            while (rcur < 8) { flushw(packbf2(acc.x, acc.y)); acc.x = acc.y = 0.f; rcur++; }
        }
    }
    __syncthreads();

    // ---------------- phase 2: GEMM 16x1024 @ 1024x128, B direct from global ----------------
    int ctb = w;
    f32x4 acc0 = {};
    const char* BfB = (const char*)Bf;
    #pragma unroll 4
    for (int kq = 0; kq < 32; kq++) {                        // K-quads of 4 kb (K=32)
        int kb = kq * 4 + lhi;
        int d = kb * 64 + ((llo ^ (kb & 15)) * 4);           // swizzled A dword index
        frag_t a  = *(const frag_t*)(&sdw[d]);
        frag_t b0 = *(const frag_t*)(BfB + ((size_t)kb * 128 + ctb * 16 + llo) * 16);
        acc0 = __builtin_amdgcn_mfma_f32_16x16x32_bf16(a, b0, acc0, 0, 0, 0);
    }

    // epilogue: C/D mapping col = lane&15, row = (lane>>4)*4 + reg
    {
        int col = ctb * 16 + llo;
        float bv = bias[col];
        #pragma unroll
        for (int rg = 0; rg < 4; rg++) {
            int rown = n0 + lhi * 4 + rg;
            if (rown < N) {
                float v = acc0[rg] + bv;
                if (relu) v = fmaxf(v, 0.f);
                if (Cout)  Cout[(size_t)rown * 128 + col] = v;
                if (hbout) hbout[(size_t)rown * 128 + col] = (unsigned short)f2bf(v);
            }
        }
    }
}

// ============================ launch ============================

extern "C" void kernel_launch(void* const* d_in, const int* in_sizes, int n_in,
                              void* d_out, int out_size, void* d_ws, size_t ws_size,
                              hipStream_t stream) {
    const float* z     = (const float*)d_in[0];
    const float* lin_w = (const float*)d_in[1];
    const float* lin_b = (const float*)d_in[2];
    const float* w1    = (const float*)d_in[3];
    const float* q1    = (const float*)d_in[4];
    const float* k1    = (const float*)d_in[5];
    const float* b1    = (const float*)d_in[6];
    const float* w2    = (const float*)d_in[7];
    const float* q2    = (const float*)d_in[8];
    const float* k2    = (const float*)d_in[9];
    const float* b2    = (const float*)d_in[10];
    const int*   ei    = (const int*)d_in[11];
    const int*   et    = (const int*)d_in[12];
    float* out = (float*)d_out;

    char* ws = (char*)d_ws;
    size_t off = 0;
    auto alloc = [&](size_t bytes) -> void* {
        void* p = ws + off;
        off += (bytes + 255) & ~(size_t)255;
        return p;
    };
    unsigned short* hb  = (unsigned short*)alloc((size_t)N_NODES * 128 * 2);  // 12.8 MB
    unsigned short* hb2 = (unsigned short*)alloc((size_t)N_NODES * 128 * 2);  // 12.8 MB
    float* Q     = (float*)alloc((size_t)N_NODES * 8 * 4);
    float* K     = (float*)alloc((size_t)N_NODES * 8 * 4);
    int* sorted  = (int*)alloc((size_t)N_EDGES * 4);
    int* deg8    = (int*)alloc((size_t)NSEG * 4);
    int* rowp8   = (int*)alloc((size_t)(NSEG + 1) * 4);
    int* cursor8 = (int*)alloc((size_t)NSEG * 4);
    int* part    = (int*)alloc(1024 * 4);
    float* wq1   = (float*)alloc(8 * 128 * 4);
    float* wk1   = (float*)alloc(8 * 128 * 4);
    float* wq2   = (float*)alloc(8 * 128 * 4);
    float* wk2   = (float*)alloc(8 * 128 * 4);
    short* Bf1   = (short*)alloc((size_t)1024 * 128 * 2);       // 256 KB bf16 blocked
    short* Bf2   = (short*)alloc((size_t)1024 * 128 * 2);       // 256 KB bf16 blocked

    const int* src = ei;
    const int* dst = ei + N_EDGES;

    const int M = NSEG;
    const int nparts = (M + 1023) / 1024;   // 391

    // 1) zero histogram
    hipMemsetAsync(deg8, 0, (size_t)M * 4, stream);

    // 2) MEGA-A: hist | wprep2 | gemm_lin  (independent work, one dispatch)
    prep_mega<<<HIST_BLKS + WPREP_BLKS + GLIN_BLKS, 256, 0, stream>>>(
        dst, et, deg8,
        w1, q1, k1, w2, q2, k2, Bf1, Bf2, wq1, wk1, wq2, wk2,
        z, lin_w, lin_b, hb);

    // 3-5) scan chain
    scan_part<<<nparts, 256, 0, stream>>>(deg8, part, M);
    scan_mid<<<1, 512, 0, stream>>>(part, nparts, rowp8, M);
    scan_fix<<<nparts, 256, 0, stream>>>(deg8, part, rowp8, cursor8, M);

    // 6) MEGA-B: fill | qk-layer-1  (independent work, one dispatch)
    fill_qk<<<HIST_BLKS + QK_BLKS, 256, 0, stream>>>(
        src, dst, et, cursor8, sorted, hb, wq1, wk1, Q, K);

    int fgrid = (N_NODES + 15) / 16;     // 3125
    int qgrid = (N_NODES + 255) / 256;   // 196

    // 7) layer 1: hb -> hb2 (relu, bf16)
    fused_agg_gemm<<<fgrid, 512, 0, stream>>>(hb, Q, K, rowp8, sorted, Bf1, b1,
                                              (float*)nullptr, hb2, N_NODES, 1);

    // 8) qk layer 2
    qk_table_kernel<<<qgrid, 256, 0, stream>>>(hb2, wq2, wk2, Q, K, N_NODES);

    // 9) layer 2: hb2 -> out (no relu, fp32)
    fused_agg_gemm<<<fgrid, 512, 0, stream>>>(hb2, Q, K, rowp8, sorted, Bf2, b2,
                                              out, (unsigned short*)nullptr, N_NODES, 0);
}